// Round 11
// baseline (385.144 us; speedup 1.0000x reference)
//
#include <hip/hip_runtime.h>
#include <cstddef>

constexpr int Bn = 4096;
constexpr int Sn = 200;
constexpr int Hn = 512;
constexpr int On = 64;
constexpr int K1 = 576; // Hn + On

constexpr size_t HNEW_OFF = (size_t)Bn * On;
constexpr size_t AW_OFF   = (size_t)Bn * On + (size_t)Bn * Hn;

// ---- ws layout (bytes), ~12 MB ----
constexpr size_t ATTNA_OFF = 0;                                   // [4096][512] bf16 attn_applied
constexpr size_t XB_OFF    = ATTNA_OFF + (size_t)Bn * Hn * 2;     // [4096][512] bf16 x
constexpr size_t HNB_OFF   = XB_OFF    + (size_t)Bn * Hn * 2;     // [4096][512] bf16 h_new

typedef __attribute__((ext_vector_type(8))) short bf16x8;
typedef __attribute__((ext_vector_type(4))) float f32x4;

__device__ __forceinline__ float sigmoidf_(float v) { return 1.f / (1.f + __expf(-v)); }
__device__ __forceinline__ unsigned short f2bf(float f) {
    unsigned u = __float_as_uint(f);
    return (unsigned short)((u + 0x7FFFu + ((u >> 16) & 1u)) >> 16);
}
// 8 fp32 -> 8 bf16 packed in uint4 (matches bf16 memory order)
__device__ __forceinline__ uint4 cvt8(const float* p) {
    float4 a = *(const float4*)p;
    float4 b = *(const float4*)(p + 4);
    uint4 r;
    r.x = (unsigned)f2bf(a.x) | ((unsigned)f2bf(a.y) << 16);
    r.y = (unsigned)f2bf(a.z) | ((unsigned)f2bf(a.w) << 16);
    r.z = (unsigned)f2bf(b.x) | ((unsigned)f2bf(b.y) << 16);
    r.w = (unsigned)f2bf(b.z) | ((unsigned)f2bf(b.w) << 16);
    return r;
}

// ---------------------------------------------------------------------------
// Fused scores GEMM + row softmax, staging straight from fp32 inputs.
// One block = 64 b-rows x 256 (200 valid) s-cols. K = 576 ([li | hidden]).
// Writes attn_weights to d_out.
// ---------------------------------------------------------------------------
__global__ __launch_bounds__(256) void scores_softmax_kernel(
    const float* __restrict__ li, const float* __restrict__ hidden,
    const float* __restrict__ attnW, const float* __restrict__ attn_b,
    float* __restrict__ dout)
{
    __shared__ unsigned short As[64 * 64];    // 8 KB
    __shared__ unsigned short Bs[256 * 64];   // 32 KB
    __shared__ float smax[4][64];
    __shared__ float ssum[4][64];

    const int tid = threadIdx.x;
    const int m0 = blockIdx.x * 64;
    const int wave = tid >> 6;
    const int lane = tid & 63;
    const int l15 = lane & 15, lg = lane >> 4;

    f32x4 acc[4][4];
#pragma unroll
    for (int i = 0; i < 4; ++i)
#pragma unroll
        for (int j = 0; j < 4; ++j) acc[i][j] = (f32x4){0.f, 0.f, 0.f, 0.f};

    for (int kc = 0; kc < K1; kc += 64) {
        __syncthreads();
        // A: 64 rows x 64 k (kc==0 -> li, else hidden at k-64), fp32 inline cvt
#pragma unroll
        for (int i = 0; i < 2; ++i) {
            int idx = tid + i * 256;
            int row = idx >> 3, ck = idx & 7;
            const float* src = (kc == 0)
                ? (li + (size_t)(m0 + row) * On + ck * 8)
                : (hidden + (size_t)(m0 + row) * Hn + (kc - 64) + ck * 8);
            uint4 v = cvt8(src);
            int byte = row * 128 + ((ck * 16) ^ ((row & 7) << 4));
            *(uint4*)((char*)As + byte) = v;
        }
        // B: 256 rows x 64 k from attn_W fp32 (rows >= Sn stage zero)
#pragma unroll
        for (int i = 0; i < 8; ++i) {
            int idx = tid + i * 256;
            int row = idx >> 3, ck = idx & 7;
            uint4 v = {0, 0, 0, 0};
            if (row < Sn) v = cvt8(attnW + (size_t)row * K1 + kc + ck * 8);
            int byte = row * 128 + ((ck * 16) ^ ((row & 7) << 4));
            *(uint4*)((char*)Bs + byte) = v;
        }
        __syncthreads();
#pragma unroll
        for (int s = 0; s < 2; ++s) {
            bf16x8 af[4], bfr[4];
#pragma unroll
            for (int i = 0; i < 4; ++i) {
                int row = i * 16 + l15;
                int byte = row * 128 + ((s * 64 + lg * 16) ^ ((row & 7) << 4));
                af[i] = *(const bf16x8*)((const char*)As + byte);
            }
#pragma unroll
            for (int j = 0; j < 4; ++j) {
                int row = wave * 64 + j * 16 + l15;
                int byte = row * 128 + ((s * 64 + lg * 16) ^ ((row & 7) << 4));
                bfr[j] = *(const bf16x8*)((const char*)Bs + byte);
            }
#pragma unroll
            for (int i = 0; i < 4; ++i)
#pragma unroll
                for (int j = 0; j < 4; ++j)
                    acc[i][j] = __builtin_amdgcn_mfma_f32_16x16x32_bf16(
                        af[i], bfr[j], acc[i][j], 0, 0, 0);
        }
    }

    // bias / -inf mask
#pragma unroll
    for (int i = 0; i < 4; ++i)
#pragma unroll
        for (int j = 0; j < 4; ++j) {
            int n = wave * 64 + j * 16 + l15;
            float bv = (n < Sn) ? attn_b[n] : 0.f;
#pragma unroll
            for (int r = 0; r < 4; ++r)
                acc[i][j][r] = (n < Sn) ? (acc[i][j][r] + bv) : -3.0e38f;
        }

#pragma unroll
    for (int i = 0; i < 4; ++i) {
#pragma unroll
        for (int r = 0; r < 4; ++r) {
            float mx = fmaxf(fmaxf(acc[i][0][r], acc[i][1][r]),
                             fmaxf(acc[i][2][r], acc[i][3][r]));
#pragma unroll
            for (int o = 8; o > 0; o >>= 1) mx = fmaxf(mx, __shfl_xor(mx, o, 64));
            if (l15 == 0) smax[wave][i * 16 + lg * 4 + r] = mx;
        }
    }
    __syncthreads();
#pragma unroll
    for (int i = 0; i < 4; ++i) {
#pragma unroll
        for (int r = 0; r < 4; ++r) {
            int row = i * 16 + lg * 4 + r;
            float mx = fmaxf(fmaxf(smax[0][row], smax[1][row]),
                             fmaxf(smax[2][row], smax[3][row]));
            float sum = 0.f;
#pragma unroll
            for (int j = 0; j < 4; ++j) {
                float e = __expf(acc[i][j][r] - mx);
                acc[i][j][r] = e;
                sum += e;
            }
#pragma unroll
            for (int o = 8; o > 0; o >>= 1) sum += __shfl_xor(sum, o, 64);
            if (l15 == 0) ssum[wave][row] = sum;
        }
    }
    __syncthreads();
#pragma unroll
    for (int i = 0; i < 4; ++i) {
#pragma unroll
        for (int r = 0; r < 4; ++r) {
            int row = i * 16 + lg * 4 + r;
            float inv = 1.f / (ssum[0][row] + ssum[1][row] + ssum[2][row] + ssum[3][row]);
#pragma unroll
            for (int j = 0; j < 4; ++j) {
                int n = wave * 64 + j * 16 + l15;
                if (n < Sn)
                    dout[AW_OFF + (size_t)(m0 + row) * Sn + n] = acc[i][j][r] * inv;
            }
        }
    }
}

// ---------------------------------------------------------------------------
// attn_applied (R6-verbatim geometry): 8 b-rows/block (512 blocks),
// 4 nontemporal 16B loads/thread. Writes attnA bf16 [4096][512].
// ---------------------------------------------------------------------------
__global__ __launch_bounds__(256) void attn_apply_kernel(
    const float* __restrict__ enc, const float* __restrict__ aw,
    unsigned short* __restrict__ attnA)
{
    __shared__ float wl[8 * Sn];
    const int tid = threadIdx.x;
    const int b0 = blockIdx.x * 8;

    for (int idx = tid; idx < 8 * Sn; idx += 256)
        wl[idx] = aw[(size_t)b0 * Sn + idx];
    __syncthreads();

    const int q = tid >> 7;          // 0/1: rows q*4 .. q*4+3
    const int hc = tid & 127;        // f32x4-chunk within the 512-col row
    const f32x4* base = (const f32x4*)enc + ((size_t)(b0 + q * 4)) * 128 + hc;

    f32x4 a0 = {0,0,0,0}, a1 = {0,0,0,0}, a2 = {0,0,0,0}, a3 = {0,0,0,0};

#pragma unroll 2
    for (int s = 0; s < Sn; ++s) {
        const f32x4* p = base + (size_t)s * (Bn * 128);
        f32x4 v0 = __builtin_nontemporal_load(p);
        f32x4 v1 = __builtin_nontemporal_load(p + 128);
        f32x4 v2 = __builtin_nontemporal_load(p + 256);
        f32x4 v3 = __builtin_nontemporal_load(p + 384);
        float w0 = wl[(q * 4 + 0) * Sn + s];
        float w1 = wl[(q * 4 + 1) * Sn + s];
        float w2 = wl[(q * 4 + 2) * Sn + s];
        float w3 = wl[(q * 4 + 3) * Sn + s];
        a0 += v0 * w0; a1 += v1 * w1; a2 += v2 * w2; a3 += v3 * w3;
    }

    const int h = hc * 4;
    f32x4 accs[4] = {a0, a1, a2, a3};
#pragma unroll
    for (int r = 0; r < 4; ++r) {
        ushort4 o = { f2bf(accs[r][0]), f2bf(accs[r][1]), f2bf(accs[r][2]), f2bf(accs[r][3]) };
        *(ushort4*)(attnA + (size_t)(b0 + q * 4 + r) * Hn + h) = o;
    }
}

// ---------------------------------------------------------------------------
// comb: xb = relu([li | attnA] @ comb_W^T + comb_b). 128x128 tiles, K=576.
// A: kc==0 from li fp32 (inline cvt), else attnA bf16. B: comb_W fp32 inline.
// ---------------------------------------------------------------------------
__global__ __launch_bounds__(256, 2) void comb_gemm_kernel(
    const float* __restrict__ li, const unsigned short* __restrict__ attnA,
    const float* __restrict__ combW, const float* __restrict__ comb_b,
    unsigned short* __restrict__ xb)
{
    __shared__ unsigned short As[128 * 64];
    __shared__ unsigned short Bs[128 * 64];

    const int tid = threadIdx.x;
    const int m0 = blockIdx.x * 128;
    const int n0 = blockIdx.y * 128;
    const int wave = tid >> 6, lane = tid & 63;
    const int wm = wave >> 1, wn = wave & 1;
    const int l15 = lane & 15, lg = lane >> 4;

    f32x4 acc[4][4];
#pragma unroll
    for (int i = 0; i < 4; ++i)
#pragma unroll
        for (int j = 0; j < 4; ++j) acc[i][j] = (f32x4){0.f, 0.f, 0.f, 0.f};

    for (int kc = 0; kc < K1; kc += 64) {
        __syncthreads();
#pragma unroll
        for (int i = 0; i < 4; ++i) {
            int idx = tid + i * 256;
            int row = idx >> 3, ck = idx & 7;
            uint4 v;
            if (kc == 0)
                v = cvt8(li + (size_t)(m0 + row) * On + ck * 8);
            else
                v = *(const uint4*)(attnA + (size_t)(m0 + row) * Hn + (kc - 64) + ck * 8);
            int byte = row * 128 + ((ck * 16) ^ ((row & 7) << 4));
            *(uint4*)((char*)As + byte) = v;
        }
#pragma unroll
        for (int i = 0; i < 4; ++i) {
            int idx = tid + i * 256;
            int row = idx >> 3, ck = idx & 7;
            uint4 v = cvt8(combW + (size_t)(n0 + row) * K1 + kc + ck * 8);
            int byte = row * 128 + ((ck * 16) ^ ((row & 7) << 4));
            *(uint4*)((char*)Bs + byte) = v;
        }
        __syncthreads();
#pragma unroll
        for (int s = 0; s < 2; ++s) {
            bf16x8 af[4], bfr[4];
#pragma unroll
            for (int i = 0; i < 4; ++i) {
                int row = wm * 64 + i * 16 + l15;
                int byte = row * 128 + ((s * 64 + lg * 16) ^ ((row & 7) << 4));
                af[i] = *(const bf16x8*)((const char*)As + byte);
            }
#pragma unroll
            for (int j = 0; j < 4; ++j) {
                int row = wn * 64 + j * 16 + l15;
                int byte = row * 128 + ((s * 64 + lg * 16) ^ ((row & 7) << 4));
                bfr[j] = *(const bf16x8*)((const char*)Bs + byte);
            }
#pragma unroll
            for (int i = 0; i < 4; ++i)
#pragma unroll
                for (int j = 0; j < 4; ++j)
                    acc[i][j] = __builtin_amdgcn_mfma_f32_16x16x32_bf16(
                        af[i], bfr[j], acc[i][j], 0, 0, 0);
        }
    }

#pragma unroll
    for (int i = 0; i < 4; ++i) {
        int m = m0 + wm * 64 + i * 16 + lg * 4;
#pragma unroll
        for (int j = 0; j < 4; ++j) {
            int n = n0 + wn * 64 + j * 16 + l15;
            float bv = comb_b[n];
#pragma unroll
            for (int r = 0; r < 4; ++r) {
                float v = fmaxf(acc[i][j][r] + bv, 0.f);
                xb[(size_t)(m + r) * Hn + n] = f2bf(v);
            }
        }
    }
}

// ---------------------------------------------------------------------------
// Fused GRU (R6 structure): phase1 A=xb bf16, W=w_ih fp32 inline;
// phase2 A=hidden fp32 inline, W=w_hh fp32 inline. fp32 accs; GRU epilogue.
// ---------------------------------------------------------------------------
template<bool AF32>
__device__ __forceinline__ void gru_gemm_phase(
    const void* __restrict__ A, const float* __restrict__ W,
    int m0, int n0, int tid, int wm, int wn, int l15, int lg,
    unsigned short* As, unsigned short* Bs,
    f32x4 aR[2][2], f32x4 aZ[2][2], f32x4 aN[2][2])
{
    for (int kc = 0; kc < Hn; kc += 64) {
        __syncthreads();
#pragma unroll
        for (int i = 0; i < 2; ++i) {
            int idx = tid + i * 256;
            int row = idx >> 3, ck = idx & 7;
            uint4 v;
            if (AF32)
                v = cvt8((const float*)A + (size_t)(m0 + row) * Hn + kc + ck * 8);
            else
                v = *(const uint4*)((const unsigned short*)A + (size_t)(m0 + row) * Hn + kc + ck * 8);
            int byte = row * 128 + ((ck * 16) ^ ((row & 7) << 4));
            *(uint4*)((char*)As + byte) = v;
        }
#pragma unroll
        for (int g = 0; g < 3; ++g)
#pragma unroll
            for (int i = 0; i < 2; ++i) {
                int idx = tid + i * 256;
                int row = idx >> 3, ck = idx & 7;
                uint4 v = cvt8(W + (size_t)(g * Hn + n0 + row) * Hn + kc + ck * 8);
                int byte = row * 128 + ((ck * 16) ^ ((row & 7) << 4));
                *(uint4*)((char*)Bs + g * 8192 + byte) = v;
            }
        __syncthreads();
#pragma unroll
        for (int s = 0; s < 2; ++s) {
            bf16x8 af[2], bf0[2], bf1[2], bf2[2];
#pragma unroll
            for (int i = 0; i < 2; ++i) {
                int row = wm * 32 + i * 16 + l15;
                int byte = row * 128 + ((s * 64 + lg * 16) ^ ((row & 7) << 4));
                af[i] = *(const bf16x8*)((const char*)As + byte);
            }
#pragma unroll
            for (int j = 0; j < 2; ++j) {
                int row = wn * 32 + j * 16 + l15;
                int byte = row * 128 + ((s * 64 + lg * 16) ^ ((row & 7) << 4));
                bf0[j] = *(const bf16x8*)((const char*)Bs + 0 * 8192 + byte);
                bf1[j] = *(const bf16x8*)((const char*)Bs + 1 * 8192 + byte);
                bf2[j] = *(const bf16x8*)((const char*)Bs + 2 * 8192 + byte);
            }
#pragma unroll
            for (int i = 0; i < 2; ++i)
#pragma unroll
                for (int j = 0; j < 2; ++j) {
                    aR[i][j] = __builtin_amdgcn_mfma_f32_16x16x32_bf16(af[i], bf0[j], aR[i][j], 0, 0, 0);
                    aZ[i][j] = __builtin_amdgcn_mfma_f32_16x16x32_bf16(af[i], bf1[j], aZ[i][j], 0, 0, 0);
                    aN[i][j] = __builtin_amdgcn_mfma_f32_16x16x32_bf16(af[i], bf2[j], aN[i][j], 0, 0, 0);
                }
        }
    }
}

__global__ __launch_bounds__(256, 2) void gru_fused_kernel(
    const unsigned short* __restrict__ xb, const float* __restrict__ hidden,
    const float* __restrict__ wih, const float* __restrict__ whh,
    const float* __restrict__ b_ih, const float* __restrict__ b_hh,
    float* __restrict__ dout, unsigned short* __restrict__ hnewb)
{
    __shared__ unsigned short As[64 * 64];      // 8 KB
    __shared__ unsigned short Bs[3 * 64 * 64];  // 24 KB

    const int tid = threadIdx.x;
    const int m0 = blockIdx.x * 64;
    const int n0 = blockIdx.y * 64;
    const int wave = tid >> 6, lane = tid & 63;
    const int wm = wave >> 1, wn = wave & 1;
    const int l15 = lane & 15, lg = lane >> 4;

    f32x4 aR[2][2], aZ[2][2], aN0[2][2], aN1[2][2];
#pragma unroll
    for (int i = 0; i < 2; ++i)
#pragma unroll
        for (int j = 0; j < 2; ++j) {
            aR[i][j] = (f32x4){0.f, 0.f, 0.f, 0.f};
            aZ[i][j] = (f32x4){0.f, 0.f, 0.f, 0.f};
            aN0[i][j] = (f32x4){0.f, 0.f, 0.f, 0.f};
            aN1[i][j] = (f32x4){0.f, 0.f, 0.f, 0.f};
        }

    gru_gemm_phase<false>(xb, wih, m0, n0, tid, wm, wn, l15, lg, As, Bs, aR, aZ, aN0);
    gru_gemm_phase<true>(hidden, whh, m0, n0, tid, wm, wn, l15, lg, As, Bs, aR, aZ, aN1);

#pragma unroll
    for (int j = 0; j < 2; ++j) {
        const int n = n0 + wn * 32 + j * 16 + l15;
        const float bR = b_ih[n] + b_hh[n];
        const float bZ = b_ih[Hn + n] + b_hh[Hn + n];
        const float bI = b_ih[2 * Hn + n];
        const float bH = b_hh[2 * Hn + n];
#pragma unroll
        for (int i = 0; i < 2; ++i) {
            const int mb = m0 + wm * 32 + i * 16 + lg * 4;
#pragma unroll
            for (int r = 0; r < 4; ++r) {
                const int m = mb + r;
                float h0 = hidden[(size_t)m * Hn + n];
                float rg = sigmoidf_(aR[i][j][r] + bR);
                float zg = sigmoidf_(aZ[i][j][r] + bZ);
                float ng = tanhf(aN0[i][j][r] + bI + rg * (aN1[i][j][r] + bH));
                float o = (1.f - zg) * ng + zg * h0;
                dout[HNEW_OFF + (size_t)m * Hn + n] = o;
                hnewb[(size_t)m * Hn + n] = f2bf(o);
            }
        }
    }
}

// ---------------------------------------------------------------------------
// out: out = hnewb @ out_W^T + out_b. 128x64 tiles, K=512. B fp32 inline.
// ---------------------------------------------------------------------------
__global__ __launch_bounds__(256, 2) void out_gemm_kernel(
    const unsigned short* __restrict__ hnewb, const float* __restrict__ outW,
    const float* __restrict__ out_b, float* __restrict__ dout)
{
    __shared__ unsigned short As[128 * 64];
    __shared__ unsigned short Bs[64 * 64];

    const int tid = threadIdx.x;
    const int m0 = blockIdx.x * 128;
    const int wave = tid >> 6, lane = tid & 63;
    const int wm = wave >> 1, wn = wave & 1;
    const int l15 = lane & 15, lg = lane >> 4;

    f32x4 acc[4][2];
#pragma unroll
    for (int i = 0; i < 4; ++i)
#pragma unroll
        for (int j = 0; j < 2; ++j) acc[i][j] = (f32x4){0.f, 0.f, 0.f, 0.f};

    for (int kc = 0; kc < Hn; kc += 64) {
        __syncthreads();
#pragma unroll
        for (int i = 0; i < 4; ++i) {
            int idx = tid + i * 256;
            int row = idx >> 3, ck = idx & 7;
            uint4 v = *(const uint4*)(hnewb + (size_t)(m0 + row) * Hn + kc + ck * 8);
            int byte = row * 128 + ((ck * 16) ^ ((row & 7) << 4));
            *(uint4*)((char*)As + byte) = v;
        }
#pragma unroll
        for (int i = 0; i < 2; ++i) {
            int idx = tid + i * 256;
            int row = idx >> 3, ck = idx & 7;
            uint4 v = cvt8(outW + (size_t)row * Hn + kc + ck * 8);
            int byte = row * 128 + ((ck * 16) ^ ((row & 7) << 4));
            *(uint4*)((char*)Bs + byte) = v;
        }
        __syncthreads();
#pragma unroll
        for (int s = 0; s < 2; ++s) {
            bf16x8 af[4], bfr[2];
#pragma unroll
            for (int i = 0; i < 4; ++i) {
                int row = wm * 64 + i * 16 + l15;
                int byte = row * 128 + ((s * 64 + lg * 16) ^ ((row & 7) << 4));
                af[i] = *(const bf16x8*)((const char*)As + byte);
            }
#pragma unroll
            for (int j = 0; j < 2; ++j) {
                int row = wn * 32 + j * 16 + l15;
                int byte = row * 128 + ((s * 64 + lg * 16) ^ ((row & 7) << 4));
                bfr[j] = *(const bf16x8*)((const char*)Bs + byte);
            }
#pragma unroll
            for (int i = 0; i < 4; ++i)
#pragma unroll
                for (int j = 0; j < 2; ++j)
                    acc[i][j] = __builtin_amdgcn_mfma_f32_16x16x32_bf16(
                        af[i], bfr[j], acc[i][j], 0, 0, 0);
        }
    }

#pragma unroll
    for (int i = 0; i < 4; ++i) {
        int m = m0 + wm * 64 + i * 16 + lg * 4;
#pragma unroll
        for (int j = 0; j < 2; ++j) {
            int n = wn * 32 + j * 16 + l15;
            float bv = out_b[n];
#pragma unroll
            for (int r = 0; r < 4; ++r)
                dout[(size_t)(m + r) * On + n] = acc[i][j][r] + bv;
        }
    }
}

// ---------------------------------------------------------------------------
extern "C" void kernel_launch(void* const* d_in, const int* in_sizes, int n_in,
                              void* d_out, int out_size, void* d_ws, size_t ws_size,
                              hipStream_t stream)
{
    const float* last_input = (const float*)d_in[0];
    const float* hidden     = (const float*)d_in[1];
    const float* enc        = (const float*)d_in[2];
    const float* attn_W     = (const float*)d_in[3];
    const float* attn_b     = (const float*)d_in[4];
    const float* comb_W     = (const float*)d_in[5];
    const float* comb_b     = (const float*)d_in[6];
    const float* w_ih       = (const float*)d_in[7];
    const float* w_hh       = (const float*)d_in[8];
    const float* b_ih       = (const float*)d_in[9];
    const float* b_hh       = (const float*)d_in[10];
    const float* out_W      = (const float*)d_in[11];
    const float* out_b      = (const float*)d_in[12];

    float* out = (float*)d_out;
    char*  ws  = (char*)d_ws;
    unsigned short* attnA = (unsigned short*)(ws + ATTNA_OFF);
    unsigned short* xb    = (unsigned short*)(ws + XB_OFF);
    unsigned short* hnewb = (unsigned short*)(ws + HNB_OFF);

    scores_softmax_kernel<<<Bn / 64, 256, 0, stream>>>(last_input, hidden, attn_W,
                                                       attn_b, out);
    attn_apply_kernel<<<Bn / 8, 256, 0, stream>>>(enc, out + AW_OFF, attnA);
    comb_gemm_kernel<<<dim3(Bn / 128, Hn / 128), 256, 0, stream>>>(
        last_input, attnA, comb_W, comb_b, xb);
    gru_fused_kernel<<<dim3(Bn / 64, Hn / 64), 256, 0, stream>>>(
        xb, hidden, w_ih, w_hh, b_ih, b_hh, out, hnewb);
    out_gemm_kernel<<<Bn / 128, 256, 0, stream>>>(hnewb, out_W, out_b, out);
}

// Round 14
// 322.987 us; speedup vs baseline: 1.1924x; 1.1924x over previous
//
#include <hip/hip_runtime.h>
#include <cstddef>

constexpr int Bn = 4096;
constexpr int Sn = 200;
constexpr int Hn = 512;
constexpr int On = 64;
constexpr int K1 = 576; // Hn + On

constexpr size_t HNEW_OFF = (size_t)Bn * On;
constexpr size_t AW_OFF   = (size_t)Bn * On + (size_t)Bn * Hn;

// ---- ws layout (bytes) ----
constexpr size_t CAT1B_OFF = 0;                                    // [4096][576] bf16: [li | hidden]
constexpr size_t CAT2B_OFF = CAT1B_OFF + (size_t)Bn * K1 * 2;      // [4096][576] bf16: [li | attnA]
constexpr size_t XB_OFF    = CAT2B_OFF + (size_t)Bn * K1 * 2;      // [4096][512] bf16
constexpr size_t WIHB_OFF  = XB_OFF    + (size_t)Bn * Hn * 2;      // [1536][512] bf16
constexpr size_t WHHB_OFF  = WIHB_OFF  + (size_t)3 * Hn * Hn * 2;  // [1536][512] bf16
constexpr size_t CWB_OFF   = WHHB_OFF  + (size_t)3 * Hn * Hn * 2;  // [512][576]  bf16
constexpr size_t OWB_OFF   = CWB_OFF   + (size_t)Hn * K1 * 2;      // [64][512]   bf16
constexpr size_t AWB_OFF   = OWB_OFF   + (size_t)On * Hn * 2;      // [256][576]  bf16 (padded attn_W)
constexpr size_t LOG_OFF   = AWB_OFF   + (size_t)256 * K1 * 2;     // [4096][200] fp32 logits
constexpr size_t HNB_OFF   = LOG_OFF   + (size_t)Bn * Sn * 4;      // [4096][512] bf16 h_new

typedef __attribute__((ext_vector_type(8))) short bf16x8;
typedef __attribute__((ext_vector_type(4))) float f32x4;

__device__ __forceinline__ float sigmoidf_(float v) { return 1.f / (1.f + __expf(-v)); }
__device__ __forceinline__ unsigned short f2bf(float f) {
    unsigned u = __float_as_uint(f);
    return (unsigned short)((u + 0x7FFFu + ((u >> 16) & 1u)) >> 16);
}
__device__ __forceinline__ ushort4 pack4(float4 v) {
    ushort4 o = { f2bf(v.x), f2bf(v.y), f2bf(v.z), f2bf(v.w) };
    return o;
}

// ---------------------------------------------------------------------------
// One fused convert kernel (R3-verbatim segment map).
// ---------------------------------------------------------------------------
__global__ __launch_bounds__(256) void cvt_all_kernel(
    const float* __restrict__ hidden, const float* __restrict__ wih,
    const float* __restrict__ whh, const float* __restrict__ combW,
    const float* __restrict__ outW, const float* __restrict__ attnW,
    const float* __restrict__ li,
    unsigned short* __restrict__ cat1b, unsigned short* __restrict__ cat2b,
    unsigned short* __restrict__ wihb, unsigned short* __restrict__ whhb,
    unsigned short* __restrict__ combWb, unsigned short* __restrict__ outWb,
    unsigned short* __restrict__ awWb)
{
    const int blk = blockIdx.x;
    const int t = threadIdx.x;
    if (blk < 2048) {
        size_t off = (size_t)blk * 1024 + (size_t)t * 4;
        int b = (int)(off >> 9), col = (int)(off & 511);
        float4 v = *(const float4*)(hidden + off);
        *(ushort4*)(cat1b + (size_t)b * K1 + On + col) = pack4(v);
    } else if (blk < 3584) {
        size_t off = (size_t)(blk - 2048) * 1024 + (size_t)t * 4;
        const float* s = (blk < 2816) ? wih : whh;
        unsigned short* d = (blk < 2816) ? wihb : whhb;
        if (blk >= 2816) off -= (size_t)768 * 1024;
        float4 v = *(const float4*)(s + off);
        *(ushort4*)(d + off) = pack4(v);
    } else if (blk < 3872) {
        size_t off = (size_t)(blk - 3584) * 1024 + (size_t)t * 4;
        float4 v = *(const float4*)(combW + off);
        *(ushort4*)(combWb + off) = pack4(v);
    } else if (blk < 3904) {
        size_t off = (size_t)(blk - 3872) * 1024 + (size_t)t * 4;
        float4 v = *(const float4*)(outW + off);
        *(ushort4*)(outWb + off) = pack4(v);
    } else if (blk < 4017) {
        size_t off = (size_t)(blk - 3904) * 1024 + (size_t)t * 4;
        if (off < (size_t)Sn * K1) {
            float4 v = *(const float4*)(attnW + off);
            *(ushort4*)(awWb + off) = pack4(v);
        }
    } else if (blk < 4049) {
        size_t off = (size_t)Sn * K1 + (size_t)(blk - 4017) * 1024 + (size_t)t * 4;
        if (off < (size_t)256 * K1) {
            ushort4 z = {0, 0, 0, 0};
            *(ushort4*)(awWb + off) = z;
        }
    } else {
        size_t off = (size_t)(blk - 4049) * 1024 + (size_t)t * 4;
        int b = (int)(off >> 6), col = (int)(off & 63);
        float4 v = *(const float4*)(li + off);
        ushort4 o = pack4(v);
        *(ushort4*)(cat1b + (size_t)b * K1 + col) = o;
        *(ushort4*)(cat2b + (size_t)b * K1 + col) = o;
    }
}

// ---------------------------------------------------------------------------
// Generic MFMA GEMM body: C = A@B^T + bias, 2x2 waves, BK=64, XOR-swizzle.
// ---------------------------------------------------------------------------
template<int MF, int NF, bool RELU, bool OUT_BF16>
__device__ __forceinline__ void gemm_bt_body(
    const unsigned short* __restrict__ A, int lda,
    const unsigned short* __restrict__ B,
    const float* __restrict__ bias, float* __restrict__ Cf,
    unsigned short* __restrict__ Cb, int K, int ldc,
    int m0, int n0, int nmax)
{
    constexpr int BM = 32 * MF;
    constexpr int BN = 32 * NF;
    __shared__ unsigned short As[BM * 64];
    __shared__ unsigned short Bs[BN * 64];

    const int tid = threadIdx.x;
    const int wave = tid >> 6;
    const int lane = tid & 63;
    const int wm = wave >> 1, wn = wave & 1;
    const int l15 = lane & 15, lg = lane >> 4;

    f32x4 acc[MF][NF];
#pragma unroll
    for (int i = 0; i < MF; ++i)
#pragma unroll
        for (int j = 0; j < NF; ++j) acc[i][j] = (f32x4){0.f, 0.f, 0.f, 0.f};

    for (int kc = 0; kc < K; kc += 64) {
        __syncthreads();
#pragma unroll
        for (int i = 0; i < BM * 8 / 256; ++i) {
            int idx = tid + i * 256;
            int row = idx >> 3, ck = idx & 7;
            uint4 v = *(const uint4*)(A + (size_t)(m0 + row) * lda + kc + ck * 8);
            int byte = row * 128 + ((ck * 16) ^ ((row & 7) << 4));
            *(uint4*)((char*)As + byte) = v;
        }
#pragma unroll
        for (int i = 0; i < BN * 8 / 256; ++i) {
            int idx = tid + i * 256;
            int row = idx >> 3, ck = idx & 7;
            uint4 v = *(const uint4*)(B + (size_t)(n0 + row) * K + kc + ck * 8);
            int byte = row * 128 + ((ck * 16) ^ ((row & 7) << 4));
            *(uint4*)((char*)Bs + byte) = v;
        }
        __syncthreads();
#pragma unroll
        for (int s = 0; s < 2; ++s) {
            bf16x8 af[MF], bfr[NF];
#pragma unroll
            for (int i = 0; i < MF; ++i) {
                int row = wm * (MF * 16) + i * 16 + l15;
                int byte = row * 128 + ((s * 64 + lg * 16) ^ ((row & 7) << 4));
                af[i] = *(const bf16x8*)((const char*)As + byte);
            }
#pragma unroll
            for (int j = 0; j < NF; ++j) {
                int row = wn * (NF * 16) + j * 16 + l15;
                int byte = row * 128 + ((s * 64 + lg * 16) ^ ((row & 7) << 4));
                bfr[j] = *(const bf16x8*)((const char*)Bs + byte);
            }
#pragma unroll
            for (int i = 0; i < MF; ++i)
#pragma unroll
                for (int j = 0; j < NF; ++j)
                    acc[i][j] = __builtin_amdgcn_mfma_f32_16x16x32_bf16(
                        af[i], bfr[j], acc[i][j], 0, 0, 0);
        }
    }

#pragma unroll
    for (int i = 0; i < MF; ++i) {
        int m = m0 + wm * (MF * 16) + i * 16 + lg * 4;
#pragma unroll
        for (int j = 0; j < NF; ++j) {
            int n = n0 + wn * (NF * 16) + j * 16 + l15;
            if (n < nmax) {
                float bv = bias[n];
#pragma unroll
                for (int r = 0; r < 4; ++r) {
                    float v = acc[i][j][r] + bv;
                    if (RELU) v = fmaxf(v, 0.f);
                    if (OUT_BF16) Cb[(size_t)(m + r) * ldc + n] = f2bf(v);
                    else          Cf[(size_t)(m + r) * ldc + n] = v;
                }
            }
        }
    }
}

// scores: logits = cat1b @ awWb^T + attn_b.  M=4096 N=256(mask 200) K=576.
__global__ __launch_bounds__(256, 2) void scores_gemm_kernel(
    const unsigned short* __restrict__ cat1b, const unsigned short* __restrict__ awWb,
    const float* __restrict__ attn_b, float* __restrict__ logits)
{
    gemm_bt_body<2, 2, false, false>(cat1b, K1, awWb, attn_b, logits, nullptr,
                                     K1, Sn, blockIdx.x * 64, blockIdx.y * 64, Sn);
}

// comb: xb = relu(cat2b @ combWb^T + comb_b). M=4096 N=512 K=576.
__global__ __launch_bounds__(256, 2) void comb_gemm_kernel(
    const unsigned short* __restrict__ cat2b, const unsigned short* __restrict__ combWb,
    const float* __restrict__ comb_b, unsigned short* __restrict__ xb)
{
    gemm_bt_body<4, 4, true, true>(cat2b, K1, combWb, comb_b, nullptr, xb,
                                   K1, Hn, blockIdx.x * 128, blockIdx.y * 128, Hn);
}

// out: out = hnewb @ outWb^T + out_b. M=4096 N=64 K=512.
__global__ __launch_bounds__(256, 2) void out_gemm_kernel(
    const unsigned short* __restrict__ hnewb, const unsigned short* __restrict__ outWb,
    const float* __restrict__ out_b, float* __restrict__ dout)
{
    gemm_bt_body<4, 2, false, false>(hnewb, Hn, outWb, out_b, dout, nullptr,
                                     Hn, On, blockIdx.x * 128, 0, On);
}

// ---------------------------------------------------------------------------
// Row softmax over [4096][200]: one wave per row -> attn_weights in d_out.
// ---------------------------------------------------------------------------
__global__ __launch_bounds__(256) void softmax_kernel(
    const float* __restrict__ logits, float* __restrict__ dout)
{
    const int row = blockIdx.x * 4 + (threadIdx.x >> 6);
    const int lane = threadIdx.x & 63;
    const float* lp = logits + (size_t)row * Sn;
    float v[4], e[4];
    float m = -3.0e38f;
#pragma unroll
    for (int k = 0; k < 4; ++k) {
        int s = lane + 64 * k;
        v[k] = (s < Sn) ? lp[s] : -3.0e38f;
        m = fmaxf(m, v[k]);
    }
#pragma unroll
    for (int o = 32; o > 0; o >>= 1) m = fmaxf(m, __shfl_xor(m, o, 64));
    float sum = 0.f;
#pragma unroll
    for (int k = 0; k < 4; ++k) {
        int s = lane + 64 * k;
        e[k] = (s < Sn) ? __expf(v[k] - m) : 0.f;
        sum += e[k];
    }
#pragma unroll
    for (int o = 32; o > 0; o >>= 1) sum += __shfl_xor(sum, o, 64);
    float inv = 1.f / sum;
#pragma unroll
    for (int k = 0; k < 4; ++k) {
        int s = lane + 64 * k;
        if (s < Sn) dout[AW_OFF + (size_t)row * Sn + s] = e[k] * inv;
    }
}

// ---------------------------------------------------------------------------
// attn_applied[b,h] = sum_s w[b,s]*enc[s,b,h] -> cat2b[:,64:] bf16
// 8 b-rows/block (512 blocks), 4 nontemporal 16B loads/thread,
// 16 KB contiguous per s-step.
// ---------------------------------------------------------------------------
__global__ __launch_bounds__(256) void attn_apply_kernel(
    const float* __restrict__ enc, const float* __restrict__ aw,
    unsigned short* __restrict__ cat2b)
{
    __shared__ float wl[8 * Sn];
    const int tid = threadIdx.x;
    const int b0 = blockIdx.x * 8;

    for (int idx = tid; idx < 8 * Sn; idx += 256)
        wl[idx] = aw[(size_t)b0 * Sn + idx];
    __syncthreads();

    const int q = tid >> 7;          // 0/1: rows q*4 .. q*4+3
    const int hc = tid & 127;        // f32x4-chunk within the 512-col row
    const f32x4* base = (const f32x4*)enc + ((size_t)(b0 + q * 4)) * 128 + hc;

    f32x4 a0 = {0,0,0,0}, a1 = {0,0,0,0}, a2 = {0,0,0,0}, a3 = {0,0,0,0};

#pragma unroll 2
    for (int s = 0; s < Sn; ++s) {
        const f32x4* p = base + (size_t)s * (Bn * 128);
        f32x4 v0 = __builtin_nontemporal_load(p);
        f32x4 v1 = __builtin_nontemporal_load(p + 128);
        f32x4 v2 = __builtin_nontemporal_load(p + 256);
        f32x4 v3 = __builtin_nontemporal_load(p + 384);
        float w0 = wl[(q * 4 + 0) * Sn + s];
        float w1 = wl[(q * 4 + 1) * Sn + s];
        float w2 = wl[(q * 4 + 2) * Sn + s];
        float w3 = wl[(q * 4 + 3) * Sn + s];
        a0 += v0 * w0; a1 += v1 * w1; a2 += v2 * w2; a3 += v3 * w3;
    }

    const int h = hc * 4;
    f32x4 accs[4] = {a0, a1, a2, a3};
#pragma unroll
    for (int r = 0; r < 4; ++r) {
        ushort4 o = { f2bf(accs[r][0]), f2bf(accs[r][1]), f2bf(accs[r][2]), f2bf(accs[r][3]) };
        *(ushort4*)(cat2b + (size_t)(b0 + q * 4 + r) * K1 + On + h) = o;
    }
}

// ---------------------------------------------------------------------------
// Fused GRU: r/z accumulate across both K-phases, n keeps separate fp32
// accs; elementwise GRU in epilogue.
// ---------------------------------------------------------------------------
__device__ __forceinline__ void gru_gemm_phase(
    const unsigned short* __restrict__ A, int lda,
    const unsigned short* __restrict__ W,
    int m0, int n0, int tid, int wm, int wn, int l15, int lg,
    unsigned short* As, unsigned short* Bs,
    f32x4 aR[2][2], f32x4 aZ[2][2], f32x4 aN[2][2])
{
    for (int kc = 0; kc < Hn; kc += 64) {
        __syncthreads();
#pragma unroll
        for (int i = 0; i < 2; ++i) {
            int idx = tid + i * 256;
            int row = idx >> 3, ck = idx & 7;
            uint4 v = *(const uint4*)(A + (size_t)(m0 + row) * lda + kc + ck * 8);
            int byte = row * 128 + ((ck * 16) ^ ((row & 7) << 4));
            *(uint4*)((char*)As + byte) = v;
        }
#pragma unroll
        for (int g = 0; g < 3; ++g)
#pragma unroll
            for (int i = 0; i < 2; ++i) {
                int idx = tid + i * 256;
                int row = idx >> 3, ck = idx & 7;
                uint4 v = *(const uint4*)(W + (size_t)(g * Hn + n0 + row) * Hn + kc + ck * 8);
                int byte = row * 128 + ((ck * 16) ^ ((row & 7) << 4));
                *(uint4*)((char*)Bs + g * 8192 + byte) = v;
            }
        __syncthreads();
#pragma unroll
        for (int s = 0; s < 2; ++s) {
            bf16x8 af[2], bf0[2], bf1[2], bf2[2];
#pragma unroll
            for (int i = 0; i < 2; ++i) {
                int row = wm * 32 + i * 16 + l15;
                int byte = row * 128 + ((s * 64 + lg * 16) ^ ((row & 7) << 4));
                af[i] = *(const bf16x8*)((const char*)As + byte);
            }
#pragma unroll
            for (int j = 0; j < 2; ++j) {
                int row = wn * 32 + j * 16 + l15;
                int byte = row * 128 + ((s * 64 + lg * 16) ^ ((row & 7) << 4));
                bf0[j] = *(const bf16x8*)((const char*)Bs + 0 * 8192 + byte);
                bf1[j] = *(const bf16x8*)((const char*)Bs + 1 * 8192 + byte);
                bf2[j] = *(const bf16x8*)((const char*)Bs + 2 * 8192 + byte);
            }
#pragma unroll
            for (int i = 0; i < 2; ++i)
#pragma unroll
                for (int j = 0; j < 2; ++j) {
                    aR[i][j] = __builtin_amdgcn_mfma_f32_16x16x32_bf16(af[i], bf0[j], aR[i][j], 0, 0, 0);
                    aZ[i][j] = __builtin_amdgcn_mfma_f32_16x16x32_bf16(af[i], bf1[j], aZ[i][j], 0, 0, 0);
                    aN[i][j] = __builtin_amdgcn_mfma_f32_16x16x32_bf16(af[i], bf2[j], aN[i][j], 0, 0, 0);
                }
        }
    }
}

__global__ __launch_bounds__(256, 2) void gru_fused_kernel(
    const unsigned short* __restrict__ xb, const unsigned short* __restrict__ cat1b,
    const unsigned short* __restrict__ wihb, const unsigned short* __restrict__ whhb,
    const float* __restrict__ b_ih, const float* __restrict__ b_hh,
    const float* __restrict__ hidden,
    float* __restrict__ dout, unsigned short* __restrict__ hnewb)
{
    __shared__ unsigned short As[64 * 64];      // 8 KB
    __shared__ unsigned short Bs[3 * 64 * 64];  // 24 KB

    const int tid = threadIdx.x;
    const int m0 = blockIdx.x * 64;
    const int n0 = blockIdx.y * 64;
    const int wave = tid >> 6, lane = tid & 63;
    const int wm = wave >> 1, wn = wave & 1;
    const int l15 = lane & 15, lg = lane >> 4;

    f32x4 aR[2][2], aZ[2][2], aN0[2][2], aN1[2][2];
#pragma unroll
    for (int i = 0; i < 2; ++i)
#pragma unroll
        for (int j = 0; j < 2; ++j) {
            aR[i][j] = (f32x4){0.f, 0.f, 0.f, 0.f};
            aZ[i][j] = (f32x4){0.f, 0.f, 0.f, 0.f};
            aN0[i][j] = (f32x4){0.f, 0.f, 0.f, 0.f};
            aN1[i][j] = (f32x4){0.f, 0.f, 0.f, 0.f};
        }

    gru_gemm_phase(xb, Hn, wihb, m0, n0, tid, wm, wn, l15, lg, As, Bs, aR, aZ, aN0);
    gru_gemm_phase(cat1b + On, K1, whhb, m0, n0, tid, wm, wn, l15, lg, As, Bs, aR, aZ, aN1);

#pragma unroll
    for (int j = 0; j < 2; ++j) {
        const int n = n0 + wn * 32 + j * 16 + l15;
        const float bR = b_ih[n] + b_hh[n];
        const float bZ = b_ih[Hn + n] + b_hh[Hn + n];
        const float bI = b_ih[2 * Hn + n];
        const float bH = b_hh[2 * Hn + n];
#pragma unroll
        for (int i = 0; i < 2; ++i) {
            const int mb = m0 + wm * 32 + i * 16 + lg * 4;
#pragma unroll
            for (int r = 0; r < 4; ++r) {
                const int m = mb + r;
                float h0 = hidden[(size_t)m * Hn + n];
                float rg = sigmoidf_(aR[i][j][r] + bR);
                float zg = sigmoidf_(aZ[i][j][r] + bZ);
                float ng = tanhf(aN0[i][j][r] + bI + rg * (aN1[i][j][r] + bH));
                float o = (1.f - zg) * ng + zg * h0;
                dout[HNEW_OFF + (size_t)m * Hn + n] = o;
                hnewb[(size_t)m * Hn + n] = f2bf(o);
            }
        }
    }
}

// ---------------------------------------------------------------------------
extern "C" void kernel_launch(void* const* d_in, const int* in_sizes, int n_in,
                              void* d_out, int out_size, void* d_ws, size_t ws_size,
                              hipStream_t stream)
{
    const float* last_input = (const float*)d_in[0];
    const float* hidden     = (const float*)d_in[1];
    const float* enc        = (const float*)d_in[2];
    const float* attn_W     = (const float*)d_in[3];
    const float* attn_b     = (const float*)d_in[4];
    const float* comb_W     = (const float*)d_in[5];
    const float* comb_b     = (const float*)d_in[6];
    const float* w_ih       = (const float*)d_in[7];
    const float* w_hh       = (const float*)d_in[8];
    const float* b_ih       = (const float*)d_in[9];
    const float* b_hh       = (const float*)d_in[10];
    const float* out_W      = (const float*)d_in[11];
    const float* out_b      = (const float*)d_in[12];

    float* out = (float*)d_out;
    char*  ws  = (char*)d_ws;
    unsigned short* cat1b  = (unsigned short*)(ws + CAT1B_OFF);
    unsigned short* cat2b  = (unsigned short*)(ws + CAT2B_OFF);
    unsigned short* xb     = (unsigned short*)(ws + XB_OFF);
    unsigned short* wihb   = (unsigned short*)(ws + WIHB_OFF);
    unsigned short* whhb   = (unsigned short*)(ws + WHHB_OFF);
    unsigned short* combWb = (unsigned short*)(ws + CWB_OFF);
    unsigned short* outWb  = (unsigned short*)(ws + OWB_OFF);
    unsigned short* awWb   = (unsigned short*)(ws + AWB_OFF);
    float*          logits = (float*)(ws + LOG_OFF);
    unsigned short* hnewb  = (unsigned short*)(ws + HNB_OFF);

    cvt_all_kernel<<<4305, 256, 0, stream>>>(hidden, w_ih, w_hh, comb_W, out_W,
                                             attn_W, last_input,
                                             cat1b, cat2b, wihb, whhb, combWb,
                                             outWb, awWb);
    scores_gemm_kernel<<<dim3(Bn / 64, 4), 256, 0, stream>>>(cat1b, awWb, attn_b, logits);
    softmax_kernel<<<Bn / 4, 256, 0, stream>>>(logits, out);
    attn_apply_kernel<<<Bn / 8, 256, 0, stream>>>(enc, out + AW_OFF, cat2b);
    comb_gemm_kernel<<<dim3(Bn / 128, Hn / 128), 256, 0, stream>>>(cat2b, combWb, comb_b, xb);
    gru_fused_kernel<<<dim3(Bn / 64, Hn / 64), 256, 0, stream>>>(
        xb, cat1b, wihb, whhb, b_ih, b_hh, hidden, out, hnewb);
    out_gemm_kernel<<<Bn / 128, 256, 0, stream>>>(hnewb, outWb, out_b, out);
}